// Round 6
// baseline (120.596 us; speedup 1.0000x reference)
//
#include <hip/hip_runtime.h>
#include <hip/hip_bf16.h>

#define SEQN 2048
#define SEQM 2048
#define CDIM 256
#define NB   4
#define NH   4
#define RDYMAGIC 0x7A3F19C5u

using bf16x8 = __attribute__((ext_vector_type(8))) short;
using f32x4  = __attribute__((ext_vector_type(4))) float;

__device__ inline unsigned short f2bf(float x) {
    __hip_bfloat16 h = __float2bfloat16(x);
    return *reinterpret_cast<unsigned short*>(&h);
}

// ---------------------------------------------------------------------------
// Node 1: Q/K/V projections (768 gemm blocks) + kv-mask compact (4 blocks).
// W and X staged directly from fp32 (RNE at fragment build). K/V epilogues
// wait on per-batch ready flag (proven R5). Block 0 zeroes the gemm23 flags.
// XCD remap: bx = t>>7, by = t&127 -> same-by blocks differ by 128 (=0 mod 8)
// -> same XCD -> X-slice fetched once per XCD.
// ---------------------------------------------------------------------------
__global__ __launch_bounds__(256, 4) void qkv_k(
    const float* __restrict__ Wq, const float* __restrict__ Wk,
    const float* __restrict__ Wv,
    const float* __restrict__ x1, const float* __restrict__ x2,
    const float* __restrict__ bq, const float* __restrict__ bk,
    const float* __restrict__ bv,
    unsigned short* __restrict__ qbf, unsigned short* __restrict__ kbf,
    unsigned short* __restrict__ vbf,
    const int* __restrict__ kvm, int* __restrict__ pidx, int* __restrict__ mcnt,
    unsigned int* __restrict__ rdy, unsigned int* __restrict__ hcnt,
    float qscale)
{
    __shared__ __align__(16) char qsm[35840];
    const int bid = blockIdx.x, tid = threadIdx.x;

    if (bid < NB) {
        if (bid == 0 && tid < 128) hcnt[tid] = 0;   // zero gemm23 flags
        // ---- compact kv_mask -> pidx/mcnt, publish ready flag
        int* sc = reinterpret_cast<int*>(qsm);
        const int b = bid;
        int loc[8], c = 0;
        #pragma unroll
        for (int e = 0; e < 8; ++e) {
            loc[e] = (kvm[(size_t)b * SEQM + tid * 8 + e] != 0) ? 1 : 0;
            c += loc[e];
        }
        sc[tid] = c;
        __syncthreads();
        for (int off = 1; off < 256; off <<= 1) {
            int v = (tid >= off) ? sc[tid - off] : 0;
            __syncthreads();
            sc[tid] += v;
            __syncthreads();
        }
        int p = sc[tid] - c;
        if (tid == 255) mcnt[b] = sc[255];
        #pragma unroll
        for (int e = 0; e < 8; ++e) {
            pidx[(size_t)b * SEQM + tid * 8 + e] = loc[e] ? p : -1;
            p += loc[e];
        }
        __threadfence();
        __syncthreads();
        if (tid == 0)
            __hip_atomic_store(&rdy[b], RDYMAGIC, __ATOMIC_RELEASE,
                               __HIP_MEMORY_SCOPE_AGENT);
        return;
    }

    const int g = bid - NB;                 // 0..767
    const int z = g >> 8, t = g & 255;
    const int bx = t >> 7, by = t & 127;    // XCD-friendly decode

    short (*At)[72] = reinterpret_cast<short(*)[72]>(qsm);            // 18432 B
    float (*Ts)[68] = reinterpret_cast<float(*)[68]>(qsm + 18432);    // 17408 B

    const float* W = (z == 0) ? Wq : (z == 1) ? Wk : Wv;
    const float* X = (z == 0) ? x1 : x2;
    const float* bias = (z == 0) ? bq : (z == 1) ? bk : bv;

    const int w = tid >> 6, l = tid & 63, lm = l & 15, lg = l >> 4;
    const int o0 = bx * 128, ng0 = by * 64;
    const int b = ng0 >> 11, n0 = ng0 & 2047;
    const int wo = (w >> 1) * 64, wn = (w & 1) * 32;

    f32x4 acc[4][2] = {};
    const int arow = tid >> 2, acol = (tid & 3) * 16;
    const int tr = tid >> 2, tc = (tid & 3) * 16;
    const int tg = (((tc >> 4) ^ ((tr >> 3) & 3)) << 4);

    for (int k0 = 0; k0 < 256; k0 += 64) {
        __syncthreads();
        #pragma unroll
        for (int p = 0; p < 2; ++p) {
            const float* s = &W[(size_t)(o0 + arow + 64 * p) * 256 + k0 + acol];
            unsigned int u[8];
            #pragma unroll
            for (int q = 0; q < 4; ++q) {
                float4 f = *reinterpret_cast<const float4*>(&s[4 * q]);
                u[2 * q]     = (unsigned int)f2bf(f.x) | ((unsigned int)f2bf(f.y) << 16);
                u[2 * q + 1] = (unsigned int)f2bf(f.z) | ((unsigned int)f2bf(f.w) << 16);
            }
            *reinterpret_cast<uint4*>(&At[arow + 64 * p][acol]) =
                make_uint4(u[0], u[1], u[2], u[3]);
            *reinterpret_cast<uint4*>(&At[arow + 64 * p][acol + 8]) =
                make_uint4(u[4], u[5], u[6], u[7]);
        }
        {
            const float* s = &X[((size_t)b * CDIM + k0 + tr) * SEQN + n0 + tc];
            #pragma unroll
            for (int q = 0; q < 4; ++q)
                *reinterpret_cast<float4*>(&Ts[tr][tg + 4 * q]) =
                    *reinterpret_cast<const float4*>(&s[4 * q]);
        }
        __syncthreads();
        #pragma unroll
        for (int kc = 0; kc < 2; ++kc) {
            bf16x8 a[4], bf[2];
            #pragma unroll
            for (int i = 0; i < 4; ++i)
                a[i] = *reinterpret_cast<const bf16x8*>(&At[wo + 16 * i + lm][kc * 32 + lg * 8]);
            #pragma unroll
            for (int j = 0; j < 2; ++j) {
                const int bk0 = kc * 32 + lg * 8;
                const int gcol = (((((wn >> 4) + j)) ^ ((bk0 >> 3) & 3)) << 4) | lm;
                union { unsigned int u[4]; bf16x8 v; } cv;
                #pragma unroll
                for (int e = 0; e < 4; ++e) {
                    float lo = Ts[bk0 + 2 * e][gcol];
                    float hi = Ts[bk0 + 2 * e + 1][gcol];
                    cv.u[e] = (unsigned int)f2bf(lo) | ((unsigned int)f2bf(hi) << 16);
                }
                bf[j] = cv.v;
            }
            #pragma unroll
            for (int i = 0; i < 4; ++i)
                #pragma unroll
                for (int j = 0; j < 2; ++j)
                    acc[i][j] = __builtin_amdgcn_mfma_f32_16x16x32_bf16(a[i], bf[j], acc[i][j], 0, 0, 0);
        }
    }

    if (z != 0) {
        if (tid == 0) {
            while (__hip_atomic_load(&rdy[b], __ATOMIC_ACQUIRE,
                                     __HIP_MEMORY_SCOPE_AGENT) != RDYMAGIC)
                __builtin_amdgcn_s_sleep(2);
        }
        __syncthreads();
    }

    #pragma unroll
    for (int j = 0; j < 2; ++j) {
        const int ng = ng0 + wn + 16 * j + lm;
        const int bb = ng >> 11, n = ng & 2047;
        const int pos = (z == 0) ? n : pidx[(size_t)bb * SEQM + n];
        #pragma unroll
        for (int i = 0; i < 4; ++i) {
            const int ob = o0 + wo + 16 * i + 4 * lg;
            float4 bv4 = *reinterpret_cast<const float4*>(&bias[ob]);
            float v[4] = {acc[i][j][0] + bv4.x, acc[i][j][1] + bv4.y,
                          acc[i][j][2] + bv4.z, acc[i][j][3] + bv4.w};
            if (z == 2) {
                if (pos >= 0) {
                    #pragma unroll
                    for (int r = 0; r < 4; ++r)
                        vbf[((size_t)bb * CDIM + ob + r) * SEQM + pos] = f2bf(v[r]);
                }
            } else if (pos >= 0) {
                const int hh = ob >> 6, dbase = ob & 63;
                const float sc_ = (z == 0) ? qscale : 1.0f;
                ushort4 pk;
                pk.x = f2bf(v[0] * sc_); pk.y = f2bf(v[1] * sc_);
                pk.z = f2bf(v[2] * sc_); pk.w = f2bf(v[3] * sc_);
                unsigned short* dst = (z == 0) ? qbf : kbf;
                *reinterpret_cast<ushort4*>(
                    &dst[(((size_t)bb * NH + hh) * SEQN + pos) * 64 + dbase]) = pk;
            }
        }
    }
}

// ---------------------------------------------------------------------------
// attention body (R1-verbatim): packed K/V flash attn -> catT[n][256+h*64..]
// ---------------------------------------------------------------------------
__device__ void do_attn(char* smraw,
    const unsigned short* __restrict__ qbf, const unsigned short* __restrict__ kbf,
    const unsigned short* __restrict__ vbf, const int* __restrict__ mcntg,
    unsigned short* __restrict__ catT, int bx, int h, int b)
{
    short (*Ks)[64][64] = reinterpret_cast<short(*)[64][64]>(smraw);
    short (*Vs)[64][64] = reinterpret_cast<short(*)[64][64]>(smraw + 16384);
    unsigned int (*Ps)[16][36] = reinterpret_cast<unsigned int(*)[16][36]>(smraw + 32768);

    const int tid = threadIdx.x;
    const int w = tid >> 6, l = tid & 63;
    const int lm = l & 15, lg = l >> 4;
    const int n_base = bx * 64 + w * 16;
    const size_t bhN = (size_t)(b * NH + h) * SEQN;
    const size_t cBase = (size_t)b * CDIM + h * 64;

    const int mcnt = mcntg[b];
    const int ntiles = (mcnt + 63) >> 6;

    if (ntiles == 0) {
        #pragma unroll
        for (int r = 0; r < 4; ++r) {
            int n = n_base + 4 * lg + r;
            unsigned short* dst = &catT[((size_t)b * SEQN + n) * 512 + 256 + h * 64];
            #pragma unroll
            for (int t = 0; t < 4; ++t) dst[16 * t + lm] = 0;
        }
        return;
    }

    const size_t qrow = (bhN + n_base + lm) * 64;
    bf16x8 qa0 = *reinterpret_cast<const bf16x8*>(&qbf[qrow + lg * 8]);
    bf16x8 qa1 = *reinterpret_cast<const bf16x8*>(&qbf[qrow + 32 + lg * 8]);

    f32x4 oacc[4] = {};
    float mrun = -3.0e5f, lrun = 0.f;

    const int r0 = tid >> 3, c8 = (tid & 7) * 8;
    const int c8s = c8 ^ ((r0 & 7) << 3);
    const int colr0 = (lg * 8) ^ ((lm & 7) << 3);
    const int colr1 = (32 + lg * 8) ^ ((lm & 7) << 3);

    {
        bf16x8 kr[2], vr[2];
        #pragma unroll
        for (int p = 0; p < 2; ++p) {
            kr[p] = *reinterpret_cast<const bf16x8*>(&kbf[(bhN + r0 + 32 * p) * 64 + c8]);
            vr[p] = *reinterpret_cast<const bf16x8*>(&vbf[(cBase + r0 + 32 * p) * SEQM + c8]);
        }
        #pragma unroll
        for (int p = 0; p < 2; ++p) {
            *reinterpret_cast<bf16x8*>(&Ks[0][r0 + 32 * p][c8s]) = kr[p];
            *reinterpret_cast<bf16x8*>(&Vs[0][r0 + 32 * p][c8s]) = vr[p];
        }
    }
    __syncthreads();

    for (int t64 = 0; t64 < ntiles; ++t64) {
        const int cur = t64 & 1;
        const bool has_next = (t64 < ntiles - 1);
        const int m0n = (t64 + 1) * 64;

        bf16x8 kr[2], vr[2];
        if (has_next) {
            #pragma unroll
            for (int p = 0; p < 2; ++p) {
                kr[p] = *reinterpret_cast<const bf16x8*>(
                    &kbf[(bhN + m0n + r0 + 32 * p) * 64 + c8]);
                vr[p] = *reinterpret_cast<const bf16x8*>(
                    &vbf[(cBase + r0 + 32 * p) * SEQM + m0n + c8]);
            }
        }

        f32x4 sv[4];
        __builtin_amdgcn_s_setprio(1);
        #pragma unroll
        for (int t = 0; t < 4; ++t) {
            bf16x8 ka0 = *reinterpret_cast<const bf16x8*>(&Ks[cur][16 * t + lm][colr0]);
            bf16x8 ka1 = *reinterpret_cast<const bf16x8*>(&Ks[cur][16 * t + lm][colr1]);
            f32x4 z = {0.f, 0.f, 0.f, 0.f};
            z = __builtin_amdgcn_mfma_f32_16x16x32_bf16(ka0, qa0, z, 0, 0, 0);
            z = __builtin_amdgcn_mfma_f32_16x16x32_bf16(ka1, qa1, z, 0, 0, 0);
            sv[t] = z;
        }
        __builtin_amdgcn_s_setprio(0);

        float mx = fmaxf(fmaxf(fmaxf(sv[0][0], sv[0][1]), fmaxf(sv[0][2], sv[0][3])),
                         fmaxf(fmaxf(sv[1][0], sv[1][1]), fmaxf(sv[1][2], sv[1][3])));
        mx = fmaxf(mx, fmaxf(fmaxf(fmaxf(sv[2][0], sv[2][1]), fmaxf(sv[2][2], sv[2][3])),
                             fmaxf(fmaxf(sv[3][0], sv[3][1]), fmaxf(sv[3][2], sv[3][3]))));
        mx = fmaxf(mx, __shfl_xor(mx, 16));
        mx = fmaxf(mx, __shfl_xor(mx, 32));
        const bool grew = (mx > mrun);
        float mnew = fmaxf(mrun, mx);
        float scl = exp2f(mrun - mnew);
        mrun = mnew;

        float rsum = 0.f;
        const int mrem = mcnt - t64 * 64;
        if (mrem >= 64) {
            #pragma unroll
            for (int t = 0; t < 4; ++t) {
                float p0 = exp2f(sv[t][0] - mnew);
                float p1 = exp2f(sv[t][1] - mnew);
                float p2 = exp2f(sv[t][2] - mnew);
                float p3 = exp2f(sv[t][3] - mnew);
                rsum += (p0 + p1) + (p2 + p3);
                unsigned int u0 = __builtin_amdgcn_perm(
                    __float_as_uint(p1), __float_as_uint(p0), 0x07060302u);
                unsigned int u1 = __builtin_amdgcn_perm(
                    __float_as_uint(p3), __float_as_uint(p2), 0x07060302u);
                *reinterpret_cast<uint2*>(&Ps[w][lm][8 * t + 2 * lg]) = make_uint2(u0, u1);
            }
        } else {
            #pragma unroll
            for (int t = 0; t < 4; ++t) {
                const int mb = 16 * t + 4 * lg;
                float p0 = (mb + 0 < mrem) ? exp2f(sv[t][0] - mnew) : 0.f;
                float p1 = (mb + 1 < mrem) ? exp2f(sv[t][1] - mnew) : 0.f;
                float p2 = (mb + 2 < mrem) ? exp2f(sv[t][2] - mnew) : 0.f;
                float p3 = (mb + 3 < mrem) ? exp2f(sv[t][3] - mnew) : 0.f;
                rsum += (p0 + p1) + (p2 + p3);
                unsigned int u0 = __builtin_amdgcn_perm(
                    __float_as_uint(p1), __float_as_uint(p0), 0x07060302u);
                unsigned int u1 = __builtin_amdgcn_perm(
                    __float_as_uint(p3), __float_as_uint(p2), 0x07060302u);
                *reinterpret_cast<uint2*>(&Ps[w][lm][8 * t + 2 * lg]) = make_uint2(u0, u1);
            }
        }
        rsum += __shfl_xor(rsum, 16);
        rsum += __shfl_xor(rsum, 32);
        lrun = lrun * scl + rsum;

        if (__any(grew && scl < 1.f)) {
            float sr[4];
            #pragma unroll
            for (int r = 0; r < 4; ++r) sr[r] = __shfl(scl, 4 * lg + r);
            #pragma unroll
            for (int t = 0; t < 4; ++t)
                #pragma unroll
                for (int r = 0; r < 4; ++r)
                    oacc[t][r] *= sr[r];
        }

        bf16x8 pa0 = *reinterpret_cast<const bf16x8*>(&Ps[w][lm][4 * lg]);
        bf16x8 pa1 = *reinterpret_cast<const bf16x8*>(&Ps[w][lm][16 + 4 * lg]);
        __builtin_amdgcn_s_setprio(1);
        #pragma unroll
        for (int t = 0; t < 4; ++t) {
            bf16x8 vb0 = *reinterpret_cast<const bf16x8*>(&Vs[cur][16 * t + lm][colr0]);
            bf16x8 vb1 = *reinterpret_cast<const bf16x8*>(&Vs[cur][16 * t + lm][colr1]);
            oacc[t] = __builtin_amdgcn_mfma_f32_16x16x32_bf16(pa0, vb0, oacc[t], 0, 0, 0);
            oacc[t] = __builtin_amdgcn_mfma_f32_16x16x32_bf16(pa1, vb1, oacc[t], 0, 0, 0);
        }
        __builtin_amdgcn_s_setprio(0);

        if (has_next) {
            const int nxt = cur ^ 1;
            #pragma unroll
            for (int p = 0; p < 2; ++p) {
                *reinterpret_cast<bf16x8*>(&Ks[nxt][r0 + 32 * p][c8s]) = kr[p];
                *reinterpret_cast<bf16x8*>(&Vs[nxt][r0 + 32 * p][c8s]) = vr[p];
            }
        }
        __syncthreads();
    }

    #pragma unroll
    for (int r = 0; r < 4; ++r) {
        float rinv = 1.f / __shfl(lrun, 4 * lg + r);
        int n = n_base + 4 * lg + r;
        unsigned short* dst = &catT[((size_t)b * SEQN + n) * 512 + 256 + h * 64];
        #pragma unroll
        for (int t = 0; t < 4; ++t)
            dst[16 * t + lm] = f2bf(oacc[t][r] * rinv);
    }
}

// ---------------------------------------------------------------------------
// Node 2: attn(512, XCD-swizzled) | fuse(512) | x1 transpose(512) | W2 cast(128)
// attn swizzle: XCD x owns (b,h) pairs {2x, 2x+1} -> K/V L2-resident per XCD.
// ---------------------------------------------------------------------------
__global__ __launch_bounds__(256) void fused2_k(
    const unsigned short* __restrict__ qbf, const unsigned short* __restrict__ kbf,
    const unsigned short* __restrict__ vbf, const int* __restrict__ mcnt,
    unsigned short* __restrict__ catT,
    const float* __restrict__ W1, const float* __restrict__ b1,
    const float* __restrict__ gamma, const float* __restrict__ beta,
    const float* __restrict__ mean, const float* __restrict__ var,
    const float* __restrict__ Wmh, const float* __restrict__ bmh,
    unsigned short* __restrict__ Acat, float* __restrict__ cvec,
    const float* __restrict__ x1,
    const float* __restrict__ W2, unsigned short* __restrict__ W2b)
{
    __shared__ __align__(16) char smraw[41984];
    const int bid = blockIdx.x, tid = threadIdx.x;

    if (bid < 512) {
        const int xcd = bid & 7, slot = bid >> 3;
        const int p = xcd * 2 + (slot >> 5);
        const int qt = slot & 31;
        do_attn(smraw, qbf, kbf, vbf, mcnt, catT, qt, p & 3, p >> 2);
    } else if (bid < 1024) {
        const int j = bid - 512;
        const int c = tid;
        const float s = gamma[j] * rsqrtf(var[j] + 1e-5f);
        const float* w1b = W1 + (size_t)j * 512 + 256;
        Acat[(size_t)j * 512 + c] = f2bf(s * W1[(size_t)j * 512 + c]);
        float acc = 0.f;
        for (int t = 0; t < 256; ++t)
            acc += w1b[t] * Wmh[(size_t)t * 256 + c];
        Acat[(size_t)j * 512 + 256 + c] = f2bf(s * acc);
        if (c == 0) {
            float ab = 0.f;
            for (int t = 0; t < 256; ++t) ab += w1b[t] * bmh[t];
            cvec[j] = s * (b1[j] + ab - mean[j]) + beta[j];
        }
    } else if (bid < 1536) {
        const int t = bid - 1024;
        float (*Ts)[68] = reinterpret_cast<float(*)[68]>(smraw);
        const int cx = t & 3, ny = (t >> 2) & 31, b = t >> 7;
        const int c0 = cx * 64, n0 = ny * 64;
        const int cr = tid >> 2, nc = (tid & 3) * 16;
        #pragma unroll
        for (int q = 0; q < 4; ++q) {
            float4 v = *reinterpret_cast<const float4*>(
                &x1[((size_t)b * CDIM + c0 + cr) * SEQN + n0 + nc + 4 * q]);
            *reinterpret_cast<float4*>(&Ts[cr][nc + 4 * q]) = v;
        }
        __syncthreads();
        const int nr = tid >> 2, cc = (tid & 3) * 16;
        unsigned short tmp[16];
        #pragma unroll
        for (int e = 0; e < 16; ++e) tmp[e] = f2bf(Ts[cc + e][nr]);
        unsigned short* dp = &catT[((size_t)(b * SEQN + n0 + nr)) * 512 + c0 + cc];
        #pragma unroll
        for (int q = 0; q < 4; ++q)
            *reinterpret_cast<ushort4*>(&dp[4 * q]) = *reinterpret_cast<ushort4*>(&tmp[4 * q]);
    } else {
        const int cid = bid - 1536;
        const int idx = (cid * 256 + tid) * 4;
        float4 v = *reinterpret_cast<const float4*>(&W2[idx]);
        ushort4 p; p.x = f2bf(v.x); p.y = f2bf(v.y); p.z = f2bf(v.z); p.w = f2bf(v.w);
        *reinterpret_cast<ushort4*>(&W2b[idx]) = p;
    }
}

// ---------------------------------------------------------------------------
// Node 3: gemm2 (512 producers) + gemm3 (256 consumers) in one launch.
// Producer (bid<512): hidden = relu(Acat @ cat + cvec) -> hbuf, flag hcnt[by].
// Consumer: spins until hcnt[by]==4, then out = x1 + W2b @ hidden + b2.
// Deadlock-free: LDS 27648B -> 5 blk/CU -> capacity 1280 >= 768 co-resident.
// XCD remap: same-by producer group {by,by+128,by+256,by+384} and consumer
// group {512+by,640+by} all = by mod 8 -> same XCD -> hbuf slice L2-hot.
// ---------------------------------------------------------------------------
__global__ __launch_bounds__(256) void gemm23_k(
    const unsigned short* __restrict__ Acat, const float* __restrict__ cvec,
    const unsigned short* __restrict__ W2b, const float* __restrict__ b2,
    const float* __restrict__ x1,
    const unsigned short* __restrict__ catT, unsigned short* __restrict__ hbuf,
    float* __restrict__ out, unsigned int* __restrict__ hcnt)
{
    __shared__ short At[128][72];
    __shared__ short Bt[64][72];
    const int bid = blockIdx.x, tid = threadIdx.x;
    const int w = tid >> 6, l = tid & 63, lm = l & 15, lg = l >> 4;
    const int arow = tid >> 2, acol = (tid & 3) * 16;
    const int wo = (w >> 1) * 64, wn = (w & 1) * 32;

    const bool prod = (bid < 512);
    const int g = prod ? bid : bid - 512;
    const int bx = g >> 7, by = g & 127;
    const int o0 = bx * 128, ng0 = by * 64;

    const unsigned short* W = prod ? Acat : W2b;
    const unsigned short* X = prod ? catT : hbuf;

    if (!prod) {
        if (tid == 0) {
            int sp = 0;
            while (__hip_atomic_load(&hcnt[by], __ATOMIC_ACQUIRE,
                                     __HIP_MEMORY_SCOPE_AGENT) < 4u
                   && sp < 10000000) {
                __builtin_amdgcn_s_sleep(2);
                ++sp;
            }
        }
        __syncthreads();
    }

    f32x4 acc[4][2] = {};
    for (int k0 = 0; k0 < 512; k0 += 64) {
        __syncthreads();
        #pragma unroll
        for (int p = 0; p < 2; ++p) {
            const unsigned short* s = &W[(size_t)(o0 + arow + 64 * p) * 512 + k0 + acol];
            *reinterpret_cast<bf16x8*>(&At[arow + 64 * p][acol]) =
                *reinterpret_cast<const bf16x8*>(s);
            *reinterpret_cast<bf16x8*>(&At[arow + 64 * p][acol + 8]) =
                *reinterpret_cast<const bf16x8*>(s + 8);
        }
        {
            const unsigned short* s = &X[(size_t)(ng0 + arow) * 512 + k0 + acol];
            *reinterpret_cast<bf16x8*>(&Bt[arow][acol]) =
                *reinterpret_cast<const bf16x8*>(s);
            *reinterpret_cast<bf16x8*>(&Bt[arow][acol + 8]) =
                *reinterpret_cast<const bf16x8*>(s + 8);
        }
        __syncthreads();
        #pragma unroll
        for (int kc = 0; kc < 2; ++kc) {
            bf16x8 a[4], bf[2];
            #pragma unroll
            for (int i = 0; i < 4; ++i)
                a[i] = *reinterpret_cast<const bf16x8*>(&At[wo + 16 * i + lm][kc * 32 + lg * 8]);
            #pragma unroll
            for (int j = 0; j < 2; ++j)
                bf[j] = *reinterpret_cast<const bf16x8*>(&Bt[wn + 16 * j + lm][kc * 32 + lg * 8]);
            #pragma unroll
            for (int i = 0; i < 4; ++i)
                #pragma unroll
                for (int j = 0; j < 2; ++j)
                    acc[i][j] = __builtin_amdgcn_mfma_f32_16x16x32_bf16(a[i], bf[j], acc[i][j], 0, 0, 0);
        }
    }

    if (prod) {
        #pragma unroll
        for (int j = 0; j < 2; ++j) {
            const int ng = ng0 + wn + 16 * j + lm;
            #pragma unroll
            for (int i = 0; i < 4; ++i) {
                const int ob = o0 + wo + 16 * i + 4 * lg;
                float4 bv = *reinterpret_cast<const float4*>(&cvec[ob]);
                ushort4 pk;
                pk.x = f2bf(fmaxf(acc[i][j][0] + bv.x, 0.f));
                pk.y = f2bf(fmaxf(acc[i][j][1] + bv.y, 0.f));
                pk.z = f2bf(fmaxf(acc[i][j][2] + bv.z, 0.f));
                pk.w = f2bf(fmaxf(acc[i][j][3] + bv.w, 0.f));
                *reinterpret_cast<ushort4*>(&hbuf[(size_t)ng * 512 + ob]) = pk;
            }
        }
        __syncthreads();                       // drains stores (vmcnt before barrier)
        if (tid == 0) {
            __threadfence();                   // L2 writeback for cross-XCD readers
            atomicAdd(&hcnt[by], 1u);
        }
    } else {
        #pragma unroll
        for (int j = 0; j < 2; ++j) {
            const int ng = ng0 + wn + 16 * j + lm;
            const int b = ng >> 11, n = ng & 2047;
            #pragma unroll
            for (int i = 0; i < 4; ++i) {
                const int ob = o0 + wo + 16 * i + 4 * lg;
                float4 bv = *reinterpret_cast<const float4*>(&b2[ob]);
                float v[4] = {acc[i][j][0] + bv.x, acc[i][j][1] + bv.y,
                              acc[i][j][2] + bv.z, acc[i][j][3] + bv.w};
                #pragma unroll
                for (int r = 0; r < 4; ++r) {
                    size_t ad = ((size_t)b * CDIM + ob + r) * SEQN + n;
                    out[ad] = v[r] + x1[ad];
                }
            }
        }
    }
}

// ---------------------------------------------------------------------------
extern "C" void kernel_launch(void* const* d_in, const int* in_sizes, int n_in,
                              void* d_out, int out_size, void* d_ws, size_t ws_size,
                              hipStream_t stream)
{
    (void)in_sizes; (void)n_in; (void)out_size; (void)ws_size;
    const float* x1    = (const float*)d_in[0];
    const float* x2    = (const float*)d_in[1];
    const int*   kvm   = (const int*)  d_in[2];
    const float* Wq    = (const float*)d_in[3];
    const float* bq    = (const float*)d_in[4];
    const float* Wk    = (const float*)d_in[5];
    const float* bk    = (const float*)d_in[6];
    const float* Wv    = (const float*)d_in[7];
    const float* bv    = (const float*)d_in[8];
    const float* Wmh   = (const float*)d_in[9];
    const float* bmh   = (const float*)d_in[10];
    const float* W1    = (const float*)d_in[11];
    const float* b1    = (const float*)d_in[12];
    const float* gamma = (const float*)d_in[13];
    const float* beta  = (const float*)d_in[14];
    const float* mean  = (const float*)d_in[15];
    const float* var   = (const float*)d_in[16];
    const float* W2    = (const float*)d_in[17];
    const float* b2    = (const float*)d_in[18];
    float* out = (float*)d_out;

    const size_t act = (size_t)NB * CDIM * SEQN;        // 2,097,152
    unsigned short* ws    = (unsigned short*)d_ws;
    unsigned short* qbf   = ws;                 // act
    unsigned short* kbf   = qbf   + act;        // act
    unsigned short* vbf   = kbf   + act;        // act
    unsigned short* catT  = vbf   + act;        // 2*act (8192 x 512)
    unsigned short* hbuf  = catT  + 2 * act;    // 2*act (8192 x 512)
    unsigned short* W2b   = hbuf  + 2 * act;    // 131072
    unsigned short* Acat  = W2b   + 131072;     // 262144
    float*          cvec  = (float*)(Acat + 262144);
    int*            pidx  = (int*)(cvec + 512);          // NB*2048
    int*            mcnt  = pidx + (size_t)NB * SEQM;    // NB
    unsigned int*   rdy   = (unsigned int*)(mcnt + 16);  // NB ready flags
    unsigned int*   hcnt  = rdy + 16;                    // 128 gemm23 flags

    const float qscale = 0.125f * 1.44269504088896f;   // fold 1/sqrt(D)*log2(e)

    // 1) Q|K|V projections + compact (zeroes hcnt)
    qkv_k<<<dim3(NB + 768), dim3(256), 0, stream>>>(
        Wq, Wk, Wv, x1, x2, bq, bk, bv, qbf, kbf, vbf,
        kvm, pidx, mcnt, rdy, hcnt, qscale);

    // 2) attn -> catT[256:512] | fuse -> Acat/cvec | x1^T -> catT[0:256] | W2 cast
    fused2_k<<<dim3(1664), dim3(256), 0, stream>>>(
        qbf, kbf, vbf, mcnt, catT,
        W1, b1, gamma, beta, mean, var, Wmh, bmh, Acat, cvec,
        x1, W2, W2b);

    // 3) gemm2 (producers) + gemm3 (consumers), flag-synced per 64-n slice
    gemm23_k<<<dim3(768), dim3(256), 0, stream>>>(
        Acat, cvec, W2b, b2, x1, catT, hbuf, out, hcnt);
}

// Round 7
// 91.517 us; speedup vs baseline: 1.3177x; 1.3177x over previous
//
#include <hip/hip_runtime.h>
#include <hip/hip_bf16.h>

#define SEQN 2048
#define SEQM 2048
#define CDIM 256
#define NB   4
#define NH   4
#define RDYMAGIC 0x7A3F19C5u

using bf16x8 = __attribute__((ext_vector_type(8))) short;
using f32x4  = __attribute__((ext_vector_type(4))) float;

__device__ inline unsigned short f2bf(float x) {
    __hip_bfloat16 h = __float2bfloat16(x);
    return *reinterpret_cast<unsigned short*>(&h);
}

// ---------------------------------------------------------------------------
// Node 1 (1924 blocks): compact(4) | QKV gemms(768) | fuse Wmh+BN(512) |
//   x1 transpose -> catT[0:256] (512) | W2 cast(128).
// Extras have NO dependency on qkv outputs -> pure backfill into gemm tail.
// K/V epilogues wait on per-batch ready flag (proven R5: wait is
// expected-already-done after 4 K-loop barriers). LDS 35840 -> 4 blk/CU.
// ---------------------------------------------------------------------------
__global__ __launch_bounds__(256, 4) void qkv_k(
    const float* __restrict__ Wq, const float* __restrict__ Wk,
    const float* __restrict__ Wv,
    const float* __restrict__ x1, const float* __restrict__ x2,
    const float* __restrict__ bq, const float* __restrict__ bk,
    const float* __restrict__ bv,
    unsigned short* __restrict__ qbf, unsigned short* __restrict__ kbf,
    unsigned short* __restrict__ vbf,
    const int* __restrict__ kvm, int* __restrict__ pidx, int* __restrict__ mcnt,
    unsigned int* __restrict__ rdy,
    const float* __restrict__ W1, const float* __restrict__ b1,
    const float* __restrict__ gamma, const float* __restrict__ beta,
    const float* __restrict__ mean, const float* __restrict__ var,
    const float* __restrict__ Wmh, const float* __restrict__ bmh,
    unsigned short* __restrict__ Acat, float* __restrict__ cvec,
    unsigned short* __restrict__ catT,
    const float* __restrict__ W2, unsigned short* __restrict__ W2b,
    float qscale)
{
    __shared__ __align__(16) char qsm[35840];
    const int bid = blockIdx.x, tid = threadIdx.x;

    if (bid < NB) {
        // ---- compact kv_mask -> pidx/mcnt, publish ready flag
        int* sc = reinterpret_cast<int*>(qsm);
        const int b = bid;
        int loc[8], c = 0;
        #pragma unroll
        for (int e = 0; e < 8; ++e) {
            loc[e] = (kvm[(size_t)b * SEQM + tid * 8 + e] != 0) ? 1 : 0;
            c += loc[e];
        }
        sc[tid] = c;
        __syncthreads();
        for (int off = 1; off < 256; off <<= 1) {
            int v = (tid >= off) ? sc[tid - off] : 0;
            __syncthreads();
            sc[tid] += v;
            __syncthreads();
        }
        int p = sc[tid] - c;
        if (tid == 255) mcnt[b] = sc[255];
        #pragma unroll
        for (int e = 0; e < 8; ++e) {
            pidx[(size_t)b * SEQM + tid * 8 + e] = loc[e] ? p : -1;
            p += loc[e];
        }
        __threadfence();
        __syncthreads();
        if (tid == 0)
            __hip_atomic_store(&rdy[b], RDYMAGIC, __ATOMIC_RELEASE,
                               __HIP_MEMORY_SCOPE_AGENT);
        return;
    }

    if (bid >= NB + 768) {
        const int xb = bid - (NB + 768);
        if (xb < 512) {
            // ---- fold Wmh + BatchNorm into W1 -> Acat / cvec
            const int j = xb, c = tid;
            const float s = gamma[j] * rsqrtf(var[j] + 1e-5f);
            const float* w1b = W1 + (size_t)j * 512 + 256;
            Acat[(size_t)j * 512 + c] = f2bf(s * W1[(size_t)j * 512 + c]);
            float acc = 0.f;
            for (int t = 0; t < 256; ++t)
                acc += w1b[t] * Wmh[(size_t)t * 256 + c];
            Acat[(size_t)j * 512 + 256 + c] = f2bf(s * acc);
            if (c == 0) {
                float ab = 0.f;
                for (int t = 0; t < 256; ++t) ab += w1b[t] * bmh[t];
                cvec[j] = s * (b1[j] + ab - mean[j]) + beta[j];
            }
        } else if (xb < 1024) {
            // ---- x1 fp32 -> bf16 transpose into catT[.][0:256]
            const int t = xb - 512;
            float (*Ts)[68] = reinterpret_cast<float(*)[68]>(qsm);
            const int cx = t & 3, ny = (t >> 2) & 31, b = t >> 7;
            const int c0 = cx * 64, n0 = ny * 64;
            const int cr = tid >> 2, nc = (tid & 3) * 16;
            #pragma unroll
            for (int q = 0; q < 4; ++q) {
                float4 v = *reinterpret_cast<const float4*>(
                    &x1[((size_t)b * CDIM + c0 + cr) * SEQN + n0 + nc + 4 * q]);
                *reinterpret_cast<float4*>(&Ts[cr][nc + 4 * q]) = v;
            }
            __syncthreads();
            const int nr = tid >> 2, cc = (tid & 3) * 16;
            unsigned short tmp[16];
            #pragma unroll
            for (int e = 0; e < 16; ++e) tmp[e] = f2bf(Ts[cc + e][nr]);
            unsigned short* dp = &catT[((size_t)(b * SEQN + n0 + nr)) * 512 + c0 + cc];
            #pragma unroll
            for (int q = 0; q < 4; ++q)
                *reinterpret_cast<ushort4*>(&dp[4 * q]) =
                    *reinterpret_cast<ushort4*>(&tmp[4 * q]);
        } else {
            const int cid = xb - 1024;
            const int idx = (cid * 256 + tid) * 4;
            float4 v = *reinterpret_cast<const float4*>(&W2[idx]);
            ushort4 p; p.x = f2bf(v.x); p.y = f2bf(v.y); p.z = f2bf(v.z); p.w = f2bf(v.w);
            *reinterpret_cast<ushort4*>(&W2b[idx]) = p;
        }
        return;
    }

    // ---- QKV gemm blocks
    const int g = bid - NB;                 // 0..767
    const int z = g >> 8, t = g & 255;
    const int bx = t >> 7, by = t & 127;    // same-by -> same XCD

    short (*At)[72] = reinterpret_cast<short(*)[72]>(qsm);            // 18432 B
    float (*Ts)[68] = reinterpret_cast<float(*)[68]>(qsm + 18432);    // 17408 B

    const float* W = (z == 0) ? Wq : (z == 1) ? Wk : Wv;
    const float* X = (z == 0) ? x1 : x2;
    const float* bias = (z == 0) ? bq : (z == 1) ? bk : bv;

    const int w = tid >> 6, l = tid & 63, lm = l & 15, lg = l >> 4;
    const int o0 = bx * 128, ng0 = by * 64;
    const int b = ng0 >> 11, n0 = ng0 & 2047;
    const int wo = (w >> 1) * 64, wn = (w & 1) * 32;

    f32x4 acc[4][2] = {};
    const int arow = tid >> 2, acol = (tid & 3) * 16;
    const int tr = tid >> 2, tc = (tid & 3) * 16;
    const int tg = (((tc >> 4) ^ ((tr >> 3) & 3)) << 4);

    for (int k0 = 0; k0 < 256; k0 += 64) {
        __syncthreads();
        #pragma unroll
        for (int p = 0; p < 2; ++p) {
            const float* s = &W[(size_t)(o0 + arow + 64 * p) * 256 + k0 + acol];
            unsigned int u[8];
            #pragma unroll
            for (int q = 0; q < 4; ++q) {
                float4 f = *reinterpret_cast<const float4*>(&s[4 * q]);
                u[2 * q]     = (unsigned int)f2bf(f.x) | ((unsigned int)f2bf(f.y) << 16);
                u[2 * q + 1] = (unsigned int)f2bf(f.z) | ((unsigned int)f2bf(f.w) << 16);
            }
            *reinterpret_cast<uint4*>(&At[arow + 64 * p][acol]) =
                make_uint4(u[0], u[1], u[2], u[3]);
            *reinterpret_cast<uint4*>(&At[arow + 64 * p][acol + 8]) =
                make_uint4(u[4], u[5], u[6], u[7]);
        }
        {
            const float* s = &X[((size_t)b * CDIM + k0 + tr) * SEQN + n0 + tc];
            #pragma unroll
            for (int q = 0; q < 4; ++q)
                *reinterpret_cast<float4*>(&Ts[tr][tg + 4 * q]) =
                    *reinterpret_cast<const float4*>(&s[4 * q]);
        }
        __syncthreads();
        #pragma unroll
        for (int kc = 0; kc < 2; ++kc) {
            bf16x8 a[4], bf[2];
            #pragma unroll
            for (int i = 0; i < 4; ++i)
                a[i] = *reinterpret_cast<const bf16x8*>(&At[wo + 16 * i + lm][kc * 32 + lg * 8]);
            #pragma unroll
            for (int j = 0; j < 2; ++j) {
                const int bk0 = kc * 32 + lg * 8;
                const int gcol = (((((wn >> 4) + j)) ^ ((bk0 >> 3) & 3)) << 4) | lm;
                union { unsigned int u[4]; bf16x8 v; } cv;
                #pragma unroll
                for (int e = 0; e < 4; ++e) {
                    float lo = Ts[bk0 + 2 * e][gcol];
                    float hi = Ts[bk0 + 2 * e + 1][gcol];
                    cv.u[e] = (unsigned int)f2bf(lo) | ((unsigned int)f2bf(hi) << 16);
                }
                bf[j] = cv.v;
            }
            #pragma unroll
            for (int i = 0; i < 4; ++i)
                #pragma unroll
                for (int j = 0; j < 2; ++j)
                    acc[i][j] = __builtin_amdgcn_mfma_f32_16x16x32_bf16(a[i], bf[j], acc[i][j], 0, 0, 0);
        }
    }

    if (z != 0) {
        if (tid == 0) {
            while (__hip_atomic_load(&rdy[b], __ATOMIC_ACQUIRE,
                                     __HIP_MEMORY_SCOPE_AGENT) != RDYMAGIC)
                __builtin_amdgcn_s_sleep(2);
        }
        __syncthreads();
    }

    #pragma unroll
    for (int j = 0; j < 2; ++j) {
        const int ng = ng0 + wn + 16 * j + lm;
        const int bb = ng >> 11, n = ng & 2047;
        const int pos = (z == 0) ? n : pidx[(size_t)bb * SEQM + n];
        #pragma unroll
        for (int i = 0; i < 4; ++i) {
            const int ob = o0 + wo + 16 * i + 4 * lg;
            float4 bv4 = *reinterpret_cast<const float4*>(&bias[ob]);
            float v[4] = {acc[i][j][0] + bv4.x, acc[i][j][1] + bv4.y,
                          acc[i][j][2] + bv4.z, acc[i][j][3] + bv4.w};
            if (z == 2) {
                if (pos >= 0) {
                    #pragma unroll
                    for (int r = 0; r < 4; ++r)
                        vbf[((size_t)bb * CDIM + ob + r) * SEQM + pos] = f2bf(v[r]);
                }
            } else if (pos >= 0) {
                const int hh = ob >> 6, dbase = ob & 63;
                const float sc_ = (z == 0) ? qscale : 1.0f;
                ushort4 pk;
                pk.x = f2bf(v[0] * sc_); pk.y = f2bf(v[1] * sc_);
                pk.z = f2bf(v[2] * sc_); pk.w = f2bf(v[3] * sc_);
                unsigned short* dst = (z == 0) ? qbf : kbf;
                *reinterpret_cast<ushort4*>(
                    &dst[(((size_t)bb * NH + hh) * SEQN + pos) * 64 + dbase]) = pk;
            }
        }
    }
}

// ---------------------------------------------------------------------------
// Node 2: pure flash attention over PACKED K/V (R1-verbatim body),
// XCD-swizzled: XCD x owns (b,h) pairs {2x,2x+1} -> K/V L2-resident per XCD.
// ---------------------------------------------------------------------------
__global__ __launch_bounds__(256) void attn_mfma_k(
    const unsigned short* __restrict__ qbf, const unsigned short* __restrict__ kbf,
    const unsigned short* __restrict__ vbf, const int* __restrict__ mcntg,
    unsigned short* __restrict__ catT)
{
    __shared__ short Ks[2][64][64];
    __shared__ short Vs[2][64][64];
    __shared__ unsigned int Ps[4][16][36];

    const int bid = blockIdx.x;
    const int xcd = bid & 7, slot = bid >> 3;
    const int p2 = xcd * 2 + (slot >> 5);
    const int bx = slot & 31, h = p2 & 3, b = p2 >> 2;

    const int tid = threadIdx.x;
    const int w = tid >> 6, l = tid & 63;
    const int lm = l & 15, lg = l >> 4;
    const int n_base = bx * 64 + w * 16;
    const size_t bhN = (size_t)(b * NH + h) * SEQN;
    const size_t cBase = (size_t)b * CDIM + h * 64;

    const int mcnt = mcntg[b];
    const int ntiles = (mcnt + 63) >> 6;

    if (ntiles == 0) {
        #pragma unroll
        for (int r = 0; r < 4; ++r) {
            int n = n_base + 4 * lg + r;
            unsigned short* dst = &catT[((size_t)b * SEQN + n) * 512 + 256 + h * 64];
            #pragma unroll
            for (int t = 0; t < 4; ++t) dst[16 * t + lm] = 0;
        }
        return;
    }

    const size_t qrow = (bhN + n_base + lm) * 64;
    bf16x8 qa0 = *reinterpret_cast<const bf16x8*>(&qbf[qrow + lg * 8]);
    bf16x8 qa1 = *reinterpret_cast<const bf16x8*>(&qbf[qrow + 32 + lg * 8]);

    f32x4 oacc[4] = {};
    float mrun = -3.0e5f, lrun = 0.f;

    const int r0 = tid >> 3, c8 = (tid & 7) * 8;
    const int c8s = c8 ^ ((r0 & 7) << 3);
    const int colr0 = (lg * 8) ^ ((lm & 7) << 3);
    const int colr1 = (32 + lg * 8) ^ ((lm & 7) << 3);

    {
        bf16x8 kr[2], vr[2];
        #pragma unroll
        for (int p = 0; p < 2; ++p) {
            kr[p] = *reinterpret_cast<const bf16x8*>(&kbf[(bhN + r0 + 32 * p) * 64 + c8]);
            vr[p] = *reinterpret_cast<const bf16x8*>(&vbf[(cBase + r0 + 32 * p) * SEQM + c8]);
        }
        #pragma unroll
        for (int p = 0; p < 2; ++p) {
            *reinterpret_cast<bf16x8*>(&Ks[0][r0 + 32 * p][c8s]) = kr[p];
            *reinterpret_cast<bf16x8*>(&Vs[0][r0 + 32 * p][c8s]) = vr[p];
        }
    }
    __syncthreads();

    for (int t64 = 0; t64 < ntiles; ++t64) {
        const int cur = t64 & 1;
        const bool has_next = (t64 < ntiles - 1);
        const int m0n = (t64 + 1) * 64;

        bf16x8 kr[2], vr[2];
        if (has_next) {
            #pragma unroll
            for (int p = 0; p < 2; ++p) {
                kr[p] = *reinterpret_cast<const bf16x8*>(
                    &kbf[(bhN + m0n + r0 + 32 * p) * 64 + c8]);
                vr[p] = *reinterpret_cast<const bf16x8*>(
                    &vbf[(cBase + r0 + 32 * p) * SEQM + m0n + c8]);
            }
        }

        f32x4 sv[4];
        __builtin_amdgcn_s_setprio(1);
        #pragma unroll
        for (int t = 0; t < 4; ++t) {
            bf16x8 ka0 = *reinterpret_cast<const bf16x8*>(&Ks[cur][16 * t + lm][colr0]);
            bf16x8 ka1 = *reinterpret_cast<const bf16x8*>(&Ks[cur][16 * t + lm][colr1]);
            f32x4 z = {0.f, 0.f, 0.f, 0.f};
            z = __builtin_amdgcn_mfma_f32_16x16x32_bf16(ka0, qa0, z, 0, 0, 0);
            z = __builtin_amdgcn_mfma_f32_16x16x32_bf16(ka1, qa1, z, 0, 0, 0);
            sv[t] = z;
        }
        __builtin_amdgcn_s_setprio(0);

        float mx = fmaxf(fmaxf(fmaxf(sv[0][0], sv[0][1]), fmaxf(sv[0][2], sv[0][3])),
                         fmaxf(fmaxf(sv[1][0], sv[1][1]), fmaxf(sv[1][2], sv[1][3])));
        mx = fmaxf(mx, fmaxf(fmaxf(fmaxf(sv[2][0], sv[2][1]), fmaxf(sv[2][2], sv[2][3])),
                             fmaxf(fmaxf(sv[3][0], sv[3][1]), fmaxf(sv[3][2], sv[3][3]))));
        mx = fmaxf(mx, __shfl_xor(mx, 16));
        mx = fmaxf(mx, __shfl_xor(mx, 32));
        const bool grew = (mx > mrun);
        float mnew = fmaxf(mrun, mx);
        float scl = exp2f(mrun - mnew);
        mrun = mnew;

        float rsum = 0.f;
        const int mrem = mcnt - t64 * 64;
        if (mrem >= 64) {
            #pragma unroll
            for (int t = 0; t < 4; ++t) {
                float p0 = exp2f(sv[t][0] - mnew);
                float p1 = exp2f(sv[t][1] - mnew);
                float p2 = exp2f(sv[t][2] - mnew);
                float p3 = exp2f(sv[t][3] - mnew);
                rsum += (p0 + p1) + (p2 + p3);
                unsigned int u0 = __builtin_amdgcn_perm(
                    __float_as_uint(p1), __float_as_uint(p0), 0x07060302u);
                unsigned int u1 = __builtin_amdgcn_perm(
                    __float_as_uint(p3), __float_as_uint(p2), 0x07060302u);
                *reinterpret_cast<uint2*>(&Ps[w][lm][8 * t + 2 * lg]) = make_uint2(u0, u1);
            }
        } else {
            #pragma unroll
            for (int t = 0; t < 4; ++t) {
                const int mb = 16 * t + 4 * lg;
                float p0 = (mb + 0 < mrem) ? exp2f(sv[t][0] - mnew) : 0.f;
                float p1 = (mb + 1 < mrem) ? exp2f(sv[t][1] - mnew) : 0.f;
                float p2 = (mb + 2 < mrem) ? exp2f(sv[t][2] - mnew) : 0.f;
                float p3 = (mb + 3 < mrem) ? exp2f(sv[t][3] - mnew) : 0.f;
                rsum += (p0 + p1) + (p2 + p3);
                unsigned int u0 = __builtin_amdgcn_perm(
                    __float_as_uint(p1), __float_as_uint(p0), 0x07060302u);
                unsigned int u1 = __builtin_amdgcn_perm(
                    __float_as_uint(p3), __float_as_uint(p2), 0x07060302u);
                *reinterpret_cast<uint2*>(&Ps[w][lm][8 * t + 2 * lg]) = make_uint2(u0, u1);
            }
        }
        rsum += __shfl_xor(rsum, 16);
        rsum += __shfl_xor(rsum, 32);
        lrun = lrun * scl + rsum;

        if (__any(grew && scl < 1.f)) {
            float sr[4];
            #pragma unroll
            for (int r = 0; r < 4; ++r) sr[r] = __shfl(scl, 4 * lg + r);
            #pragma unroll
            for (int t = 0; t < 4; ++t)
                #pragma unroll
                for (int r = 0; r < 4; ++r)
                    oacc[t][r] *= sr[r];
        }

        bf16x8 pa0 = *reinterpret_cast<const bf16x8*>(&Ps[w][lm][4 * lg]);
        bf16x8 pa1 = *reinterpret_cast<const bf16x8*>(&Ps[w][lm][16 + 4 * lg]);
        __builtin_amdgcn_s_setprio(1);
        #pragma unroll
        for (int t = 0; t < 4; ++t) {
            bf16x8 vb0 = *reinterpret_cast<const bf16x8*>(&Vs[cur][16 * t + lm][colr0]);
            bf16x8 vb1 = *reinterpret_cast<const bf16x8*>(&Vs[cur][16 * t + lm][colr1]);
            oacc[t] = __builtin_amdgcn_mfma_f32_16x16x32_bf16(pa0, vb0, oacc[t], 0, 0, 0);
            oacc[t] = __builtin_amdgcn_mfma_f32_16x16x32_bf16(pa1, vb1, oacc[t], 0, 0, 0);
        }
        __builtin_amdgcn_s_setprio(0);

        if (has_next) {
            const int nxt = cur ^ 1;
            #pragma unroll
            for (int p = 0; p < 2; ++p) {
                *reinterpret_cast<bf16x8*>(&Ks[nxt][r0 + 32 * p][c8s]) = kr[p];
                *reinterpret_cast<bf16x8*>(&Vs[nxt][r0 + 32 * p][c8s]) = vr[p];
            }
        }
        __syncthreads();
    }

    #pragma unroll
    for (int r = 0; r < 4; ++r) {
        float rinv = 1.f / __shfl(lrun, 4 * lg + r);
        int n = n_base + 4 * lg + r;
        unsigned short* dst = &catT[((size_t)b * SEQN + n) * 512 + 256 + h * 64];
        #pragma unroll
        for (int t = 0; t < 4; ++t)
            dst[16 * t + lm] = f2bf(oacc[t][r] * rinv);
    }
}

// ---------------------------------------------------------------------------
// Nodes 3/4: bf16 MFMA GEMM (R1-proven body), 1-D grid with mod-8-invariant
// by decode (same-by blocks share the X slice on one XCD).
// OMODE 2: bias+ReLU bf16 -> hbuf    OMODE 3: bias+residual fp32 -> out
// ---------------------------------------------------------------------------
template<int OMODE>
__global__ __launch_bounds__(256) void gemm_mfma_k(
    const unsigned short* __restrict__ W, const unsigned short* __restrict__ X,
    const float* __restrict__ bias, const float* __restrict__ res,
    unsigned short* __restrict__ obf, float* __restrict__ ofp)
{
    __shared__ short At[128][72];
    __shared__ short Bt[64][72];
    const int tid = threadIdx.x;
    const int w = tid >> 6, l = tid & 63, lm = l & 15, lg = l >> 4;
    const int g = blockIdx.x;
    const int bx = g >> 7, by = g & 127;
    const int o0 = bx * 128, ng0 = by * 64;
    const int wo = (w >> 1) * 64, wn = (w & 1) * 32;

    f32x4 acc[4][2] = {};
    const int arow = tid >> 2, acol = (tid & 3) * 16;

    for (int k0 = 0; k0 < 512; k0 += 64) {
        __syncthreads();
        #pragma unroll
        for (int p = 0; p < 2; ++p) {
            const unsigned short* s = &W[(size_t)(o0 + arow + 64 * p) * 512 + k0 + acol];
            *reinterpret_cast<bf16x8*>(&At[arow + 64 * p][acol]) =
                *reinterpret_cast<const bf16x8*>(s);
            *reinterpret_cast<bf16x8*>(&At[arow + 64 * p][acol + 8]) =
                *reinterpret_cast<const bf16x8*>(s + 8);
        }
        {
            const unsigned short* s = &X[(size_t)(ng0 + arow) * 512 + k0 + acol];
            *reinterpret_cast<bf16x8*>(&Bt[arow][acol]) =
                *reinterpret_cast<const bf16x8*>(s);
            *reinterpret_cast<bf16x8*>(&Bt[arow][acol + 8]) =
                *reinterpret_cast<const bf16x8*>(s + 8);
        }
        __syncthreads();
        #pragma unroll
        for (int kc = 0; kc < 2; ++kc) {
            bf16x8 a[4], bf[2];
            #pragma unroll
            for (int i = 0; i < 4; ++i)
                a[i] = *reinterpret_cast<const bf16x8*>(&At[wo + 16 * i + lm][kc * 32 + lg * 8]);
            #pragma unroll
            for (int j = 0; j < 2; ++j)
                bf[j] = *reinterpret_cast<const bf16x8*>(&Bt[wn + 16 * j + lm][kc * 32 + lg * 8]);
            #pragma unroll
            for (int i = 0; i < 4; ++i)
                #pragma unroll
                for (int j = 0; j < 2; ++j)
                    acc[i][j] = __builtin_amdgcn_mfma_f32_16x16x32_bf16(a[i], bf[j], acc[i][j], 0, 0, 0);
        }
    }

    #pragma unroll
    for (int j = 0; j < 2; ++j) {
        const int ng = ng0 + wn + 16 * j + lm;
        const int b = ng >> 11, n = ng & 2047;
        #pragma unroll
        for (int i = 0; i < 4; ++i) {
            const int ob = o0 + wo + 16 * i + 4 * lg;
            float4 bv = *reinterpret_cast<const float4*>(&bias[ob]);
            float v[4] = {acc[i][j][0] + bv.x, acc[i][j][1] + bv.y,
                          acc[i][j][2] + bv.z, acc[i][j][3] + bv.w};
            if (OMODE == 2) {
                ushort4 pk;
                pk.x = f2bf(fmaxf(v[0], 0.f)); pk.y = f2bf(fmaxf(v[1], 0.f));
                pk.z = f2bf(fmaxf(v[2], 0.f)); pk.w = f2bf(fmaxf(v[3], 0.f));
                *reinterpret_cast<ushort4*>(&obf[(size_t)ng * 512 + ob]) = pk;
            } else {
                #pragma unroll
                for (int r = 0; r < 4; ++r) {
                    size_t ad = ((size_t)b * CDIM + ob + r) * SEQN + n;
                    ofp[ad] = v[r] + res[ad];
                }
            }
        }
    }
}

// ---------------------------------------------------------------------------
extern "C" void kernel_launch(void* const* d_in, const int* in_sizes, int n_in,
                              void* d_out, int out_size, void* d_ws, size_t ws_size,
                              hipStream_t stream)
{
    (void)in_sizes; (void)n_in; (void)out_size; (void)ws_size;
    const float* x1    = (const float*)d_in[0];
    const float* x2    = (const float*)d_in[1];
    const int*   kvm   = (const int*)  d_in[2];
    const float* Wq    = (const float*)d_in[3];
    const float* bq    = (const float*)d_in[4];
    const float* Wk    = (const float*)d_in[5];
    const float* bk    = (const float*)d_in[6];
    const float* Wv    = (const float*)d_in[7];
    const float* bv    = (const float*)d_in[8];
    const float* Wmh   = (const float*)d_in[9];
    const float* bmh   = (const float*)d_in[10];
    const float* W1    = (const float*)d_in[11];
    const float* b1    = (const float*)d_in[12];
    const float* gamma = (const float*)d_in[13];
    const float* beta  = (const float*)d_in[14];
    const float* mean  = (const float*)d_in[15];
    const float* var   = (const float*)d_in[16];
    const float* W2    = (const float*)d_in[17];
    const float* b2    = (const float*)d_in[18];
    float* out = (float*)d_out;

    const size_t act = (size_t)NB * CDIM * SEQN;        // 2,097,152
    unsigned short* ws    = (unsigned short*)d_ws;
    unsigned short* qbf   = ws;                 // act
    unsigned short* kbf   = qbf   + act;        // act
    unsigned short* vbf   = kbf   + act;        // act
    unsigned short* catT  = vbf   + act;        // 2*act (8192 x 512)
    unsigned short* hbuf  = catT  + 2 * act;    // 2*act (8192 x 512)
    unsigned short* W2b   = hbuf  + 2 * act;    // 131072
    unsigned short* Acat  = W2b   + 131072;     // 262144
    float*          cvec  = (float*)(Acat + 262144);
    int*            pidx  = (int*)(cvec + 512);          // NB*2048
    int*            mcnt  = pidx + (size_t)NB * SEQM;    // NB
    unsigned int*   rdy   = (unsigned int*)(mcnt + 16);  // NB ready flags

    const float qscale = 0.125f * 1.44269504088896f;   // fold 1/sqrt(D)*log2(e)

    // 1) compact | QKV gemms | fuse | x1^T | W2 cast  (1924 blocks)
    qkv_k<<<dim3(NB + 768 + 1152), dim3(256), 0, stream>>>(
        Wq, Wk, Wv, x1, x2, bq, bk, bv, qbf, kbf, vbf,
        kvm, pidx, mcnt, rdy,
        W1, b1, gamma, beta, mean, var, Wmh, bmh, Acat, cvec,
        catT, W2, W2b, qscale);

    // 2) pure attention -> catT[256:512]
    attn_mfma_k<<<dim3(512), dim3(256), 0, stream>>>(
        qbf, kbf, vbf, mcnt, catT);

    // 3) hidden = relu(Acat @ cat + cvec)
    gemm_mfma_k<2><<<dim3(512), dim3(256), 0, stream>>>(
        Acat, catT, cvec, nullptr, hbuf, nullptr);

    // 4) out = x1 + W2 @ hidden + b2
    gemm_mfma_k<3><<<dim3(256), dim3(256), 0, stream>>>(
        W2b, hbuf, b2, x1, nullptr, out);
}

// Round 8
// 74.157 us; speedup vs baseline: 1.6262x; 1.2341x over previous
//
#include <hip/hip_runtime.h>
#include <hip/hip_bf16.h>

#define SEQN 2048
#define SEQM 2048
#define CDIM 256
#define NB   4
#define NH   4
#define RDYMAGIC 0x7A3F19C5u

using bf16x8 = __attribute__((ext_vector_type(8))) short;
using f32x4  = __attribute__((ext_vector_type(4))) float;

__device__ inline unsigned short f2bf(float x) {
    __hip_bfloat16 h = __float2bfloat16(x);
    return *reinterpret_cast<unsigned short*>(&h);
}

// ---------------------------------------------------------------------------
// Node 1: Q/K/V projections (768 gemm blocks) + kv-mask compact (4 blocks).
// R5-verbatim except XCD decode: bx=t>>7, by=t&127 (same-by -> same XCD).
// ---------------------------------------------------------------------------
__global__ __launch_bounds__(256, 4) void qkv_k(
    const float* __restrict__ Wq, const float* __restrict__ Wk,
    const float* __restrict__ Wv,
    const float* __restrict__ x1, const float* __restrict__ x2,
    const float* __restrict__ bq, const float* __restrict__ bk,
    const float* __restrict__ bv,
    unsigned short* __restrict__ qbf, unsigned short* __restrict__ kbf,
    unsigned short* __restrict__ vbf,
    const int* __restrict__ kvm, int* __restrict__ pidx, int* __restrict__ mcnt,
    unsigned int* __restrict__ rdy, float qscale)
{
    __shared__ __align__(16) char qsm[35840];
    const int bid = blockIdx.x, tid = threadIdx.x;

    if (bid < NB) {
        int* sc = reinterpret_cast<int*>(qsm);
        const int b = bid;
        int loc[8], c = 0;
        #pragma unroll
        for (int e = 0; e < 8; ++e) {
            loc[e] = (kvm[(size_t)b * SEQM + tid * 8 + e] != 0) ? 1 : 0;
            c += loc[e];
        }
        sc[tid] = c;
        __syncthreads();
        for (int off = 1; off < 256; off <<= 1) {
            int v = (tid >= off) ? sc[tid - off] : 0;
            __syncthreads();
            sc[tid] += v;
            __syncthreads();
        }
        int p = sc[tid] - c;
        if (tid == 255) mcnt[b] = sc[255];
        #pragma unroll
        for (int e = 0; e < 8; ++e) {
            pidx[(size_t)b * SEQM + tid * 8 + e] = loc[e] ? p : -1;
            p += loc[e];
        }
        __threadfence();
        __syncthreads();
        if (tid == 0)
            __hip_atomic_store(&rdy[b], RDYMAGIC, __ATOMIC_RELEASE,
                               __HIP_MEMORY_SCOPE_AGENT);
        return;
    }

    const int g = bid - NB;                 // 0..767
    const int z = g >> 8, t = g & 255;
    const int bx = t >> 7, by = t & 127;    // XCD-friendly decode

    short (*At)[72] = reinterpret_cast<short(*)[72]>(qsm);            // 18432 B
    float (*Ts)[68] = reinterpret_cast<float(*)[68]>(qsm + 18432);    // 17408 B

    const float* W = (z == 0) ? Wq : (z == 1) ? Wk : Wv;
    const float* X = (z == 0) ? x1 : x2;
    const float* bias = (z == 0) ? bq : (z == 1) ? bk : bv;

    const int w = tid >> 6, l = tid & 63, lm = l & 15, lg = l >> 4;
    const int o0 = bx * 128, ng0 = by * 64;
    const int b = ng0 >> 11, n0 = ng0 & 2047;
    const int wo = (w >> 1) * 64, wn = (w & 1) * 32;

    f32x4 acc[4][2] = {};
    const int arow = tid >> 2, acol = (tid & 3) * 16;
    const int tr = tid >> 2, tc = (tid & 3) * 16;
    const int tg = (((tc >> 4) ^ ((tr >> 3) & 3)) << 4);

    for (int k0 = 0; k0 < 256; k0 += 64) {
        __syncthreads();
        #pragma unroll
        for (int p = 0; p < 2; ++p) {
            const float* s = &W[(size_t)(o0 + arow + 64 * p) * 256 + k0 + acol];
            unsigned int u[8];
            #pragma unroll
            for (int q = 0; q < 4; ++q) {
                float4 f = *reinterpret_cast<const float4*>(&s[4 * q]);
                u[2 * q]     = (unsigned int)f2bf(f.x) | ((unsigned int)f2bf(f.y) << 16);
                u[2 * q + 1] = (unsigned int)f2bf(f.z) | ((unsigned int)f2bf(f.w) << 16);
            }
            *reinterpret_cast<uint4*>(&At[arow + 64 * p][acol]) =
                make_uint4(u[0], u[1], u[2], u[3]);
            *reinterpret_cast<uint4*>(&At[arow + 64 * p][acol + 8]) =
                make_uint4(u[4], u[5], u[6], u[7]);
        }
        {
            const float* s = &X[((size_t)b * CDIM + k0 + tr) * SEQN + n0 + tc];
            #pragma unroll
            for (int q = 0; q < 4; ++q)
                *reinterpret_cast<float4*>(&Ts[tr][tg + 4 * q]) =
                    *reinterpret_cast<const float4*>(&s[4 * q]);
        }
        __syncthreads();
        #pragma unroll
        for (int kc = 0; kc < 2; ++kc) {
            bf16x8 a[4], bf[2];
            #pragma unroll
            for (int i = 0; i < 4; ++i)
                a[i] = *reinterpret_cast<const bf16x8*>(&At[wo + 16 * i + lm][kc * 32 + lg * 8]);
            #pragma unroll
            for (int j = 0; j < 2; ++j) {
                const int bk0 = kc * 32 + lg * 8;
                const int gcol = (((((wn >> 4) + j)) ^ ((bk0 >> 3) & 3)) << 4) | lm;
                union { unsigned int u[4]; bf16x8 v; } cv;
                #pragma unroll
                for (int e = 0; e < 4; ++e) {
                    float lo = Ts[bk0 + 2 * e][gcol];
                    float hi = Ts[bk0 + 2 * e + 1][gcol];
                    cv.u[e] = (unsigned int)f2bf(lo) | ((unsigned int)f2bf(hi) << 16);
                }
                bf[j] = cv.v;
            }
            #pragma unroll
            for (int i = 0; i < 4; ++i)
                #pragma unroll
                for (int j = 0; j < 2; ++j)
                    acc[i][j] = __builtin_amdgcn_mfma_f32_16x16x32_bf16(a[i], bf[j], acc[i][j], 0, 0, 0);
        }
    }

    if (z != 0) {
        if (tid == 0) {
            while (__hip_atomic_load(&rdy[b], __ATOMIC_ACQUIRE,
                                     __HIP_MEMORY_SCOPE_AGENT) != RDYMAGIC)
                __builtin_amdgcn_s_sleep(2);
        }
        __syncthreads();
    }

    #pragma unroll
    for (int j = 0; j < 2; ++j) {
        const int ng = ng0 + wn + 16 * j + lm;
        const int bb = ng >> 11, n = ng & 2047;
        const int pos = (z == 0) ? n : pidx[(size_t)bb * SEQM + n];
        #pragma unroll
        for (int i = 0; i < 4; ++i) {
            const int ob = o0 + wo + 16 * i + 4 * lg;
            float4 bv4 = *reinterpret_cast<const float4*>(&bias[ob]);
            float v[4] = {acc[i][j][0] + bv4.x, acc[i][j][1] + bv4.y,
                          acc[i][j][2] + bv4.z, acc[i][j][3] + bv4.w};
            if (z == 2) {
                if (pos >= 0) {
                    #pragma unroll
                    for (int r = 0; r < 4; ++r)
                        vbf[((size_t)bb * CDIM + ob + r) * SEQM + pos] = f2bf(v[r]);
                }
            } else if (pos >= 0) {
                const int hh = ob >> 6, dbase = ob & 63;
                const float sc_ = (z == 0) ? qscale : 1.0f;
                ushort4 pk;
                pk.x = f2bf(v[0] * sc_); pk.y = f2bf(v[1] * sc_);
                pk.z = f2bf(v[2] * sc_); pk.w = f2bf(v[3] * sc_);
                unsigned short* dst = (z == 0) ? qbf : kbf;
                *reinterpret_cast<ushort4*>(
                    &dst[(((size_t)bb * NH + hh) * SEQN + pos) * 64 + dbase]) = pk;
            }
        }
    }
}

// ---------------------------------------------------------------------------
// attention body (R1-verbatim): packed K/V flash attn -> catT[n][256+h*64..]
// ---------------------------------------------------------------------------
__device__ void do_attn(char* smraw,
    const unsigned short* __restrict__ qbf, const unsigned short* __restrict__ kbf,
    const unsigned short* __restrict__ vbf, const int* __restrict__ mcntg,
    unsigned short* __restrict__ catT, int bx, int h, int b)
{
    short (*Ks)[64][64] = reinterpret_cast<short(*)[64][64]>(smraw);
    short (*Vs)[64][64] = reinterpret_cast<short(*)[64][64]>(smraw + 16384);
    unsigned int (*Ps)[16][36] = reinterpret_cast<unsigned int(*)[16][36]>(smraw + 32768);

    const int tid = threadIdx.x;
    const int w = tid >> 6, l = tid & 63;
    const int lm = l & 15, lg = l >> 4;
    const int n_base = bx * 64 + w * 16;
    const size_t bhN = (size_t)(b * NH + h) * SEQN;
    const size_t cBase = (size_t)b * CDIM + h * 64;

    const int mcnt = mcntg[b];
    const int ntiles = (mcnt + 63) >> 6;

    if (ntiles == 0) {
        #pragma unroll
        for (int r = 0; r < 4; ++r) {
            int n = n_base + 4 * lg + r;
            unsigned short* dst = &catT[((size_t)b * SEQN + n) * 512 + 256 + h * 64];
            #pragma unroll
            for (int t = 0; t < 4; ++t) dst[16 * t + lm] = 0;
        }
        return;
    }

    const size_t qrow = (bhN + n_base + lm) * 64;
    bf16x8 qa0 = *reinterpret_cast<const bf16x8*>(&qbf[qrow + lg * 8]);
    bf16x8 qa1 = *reinterpret_cast<const bf16x8*>(&qbf[qrow + 32 + lg * 8]);

    f32x4 oacc[4] = {};
    float mrun = -3.0e5f, lrun = 0.f;

    const int r0 = tid >> 3, c8 = (tid & 7) * 8;
    const int c8s = c8 ^ ((r0 & 7) << 3);
    const int colr0 = (lg * 8) ^ ((lm & 7) << 3);
    const int colr1 = (32 + lg * 8) ^ ((lm & 7) << 3);

    {
        bf16x8 kr[2], vr[2];
        #pragma unroll
        for (int p = 0; p < 2; ++p) {
            kr[p] = *reinterpret_cast<const bf16x8*>(&kbf[(bhN + r0 + 32 * p) * 64 + c8]);
            vr[p] = *reinterpret_cast<const bf16x8*>(&vbf[(cBase + r0 + 32 * p) * SEQM + c8]);
        }
        #pragma unroll
        for (int p = 0; p < 2; ++p) {
            *reinterpret_cast<bf16x8*>(&Ks[0][r0 + 32 * p][c8s]) = kr[p];
            *reinterpret_cast<bf16x8*>(&Vs[0][r0 + 32 * p][c8s]) = vr[p];
        }
    }
    __syncthreads();

    for (int t64 = 0; t64 < ntiles; ++t64) {
        const int cur = t64 & 1;
        const bool has_next = (t64 < ntiles - 1);
        const int m0n = (t64 + 1) * 64;

        bf16x8 kr[2], vr[2];
        if (has_next) {
            #pragma unroll
            for (int p = 0; p < 2; ++p) {
                kr[p] = *reinterpret_cast<const bf16x8*>(
                    &kbf[(bhN + m0n + r0 + 32 * p) * 64 + c8]);
                vr[p] = *reinterpret_cast<const bf16x8*>(
                    &vbf[(cBase + r0 + 32 * p) * SEQM + m0n + c8]);
            }
        }

        f32x4 sv[4];
        __builtin_amdgcn_s_setprio(1);
        #pragma unroll
        for (int t = 0; t < 4; ++t) {
            bf16x8 ka0 = *reinterpret_cast<const bf16x8*>(&Ks[cur][16 * t + lm][colr0]);
            bf16x8 ka1 = *reinterpret_cast<const bf16x8*>(&Ks[cur][16 * t + lm][colr1]);
            f32x4 z = {0.f, 0.f, 0.f, 0.f};
            z = __builtin_amdgcn_mfma_f32_16x16x32_bf16(ka0, qa0, z, 0, 0, 0);
            z = __builtin_amdgcn_mfma_f32_16x16x32_bf16(ka1, qa1, z, 0, 0, 0);
            sv[t] = z;
        }
        __builtin_amdgcn_s_setprio(0);

        float mx = fmaxf(fmaxf(fmaxf(sv[0][0], sv[0][1]), fmaxf(sv[0][2], sv[0][3])),
                         fmaxf(fmaxf(sv[1][0], sv[1][1]), fmaxf(sv[1][2], sv[1][3])));
        mx = fmaxf(mx, fmaxf(fmaxf(fmaxf(sv[2][0], sv[2][1]), fmaxf(sv[2][2], sv[2][3])),
                             fmaxf(fmaxf(sv[3][0], sv[3][1]), fmaxf(sv[3][2], sv[3][3]))));
        mx = fmaxf(mx, __shfl_xor(mx, 16));
        mx = fmaxf(mx, __shfl_xor(mx, 32));
        const bool grew = (mx > mrun);
        float mnew = fmaxf(mrun, mx);
        float scl = exp2f(mrun - mnew);
        mrun = mnew;

        float rsum = 0.f;
        const int mrem = mcnt - t64 * 64;
        if (mrem >= 64) {
            #pragma unroll
            for (int t = 0; t < 4; ++t) {
                float p0 = exp2f(sv[t][0] - mnew);
                float p1 = exp2f(sv[t][1] - mnew);
                float p2 = exp2f(sv[t][2] - mnew);
                float p3 = exp2f(sv[t][3] - mnew);
                rsum += (p0 + p1) + (p2 + p3);
                unsigned int u0 = __builtin_amdgcn_perm(
                    __float_as_uint(p1), __float_as_uint(p0), 0x07060302u);
                unsigned int u1 = __builtin_amdgcn_perm(
                    __float_as_uint(p3), __float_as_uint(p2), 0x07060302u);
                *reinterpret_cast<uint2*>(&Ps[w][lm][8 * t + 2 * lg]) = make_uint2(u0, u1);
            }
        } else {
            #pragma unroll
            for (int t = 0; t < 4; ++t) {
                const int mb = 16 * t + 4 * lg;
                float p0 = (mb + 0 < mrem) ? exp2f(sv[t][0] - mnew) : 0.f;
                float p1 = (mb + 1 < mrem) ? exp2f(sv[t][1] - mnew) : 0.f;
                float p2 = (mb + 2 < mrem) ? exp2f(sv[t][2] - mnew) : 0.f;
                float p3 = (mb + 3 < mrem) ? exp2f(sv[t][3] - mnew) : 0.f;
                rsum += (p0 + p1) + (p2 + p3);
                unsigned int u0 = __builtin_amdgcn_perm(
                    __float_as_uint(p1), __float_as_uint(p0), 0x07060302u);
                unsigned int u1 = __builtin_amdgcn_perm(
                    __float_as_uint(p3), __float_as_uint(p2), 0x07060302u);
                *reinterpret_cast<uint2*>(&Ps[w][lm][8 * t + 2 * lg]) = make_uint2(u0, u1);
            }
        }
        rsum += __shfl_xor(rsum, 16);
        rsum += __shfl_xor(rsum, 32);
        lrun = lrun * scl + rsum;

        if (__any(grew && scl < 1.f)) {
            float sr[4];
            #pragma unroll
            for (int r = 0; r < 4; ++r) sr[r] = __shfl(scl, 4 * lg + r);
            #pragma unroll
            for (int t = 0; t < 4; ++t)
                #pragma unroll
                for (int r = 0; r < 4; ++r)
                    oacc[t][r] *= sr[r];
        }

        bf16x8 pa0 = *reinterpret_cast<const bf16x8*>(&Ps[w][lm][4 * lg]);
        bf16x8 pa1 = *reinterpret_cast<const bf16x8*>(&Ps[w][lm][16 + 4 * lg]);
        __builtin_amdgcn_s_setprio(1);
        #pragma unroll
        for (int t = 0; t < 4; ++t) {
            bf16x8 vb0 = *reinterpret_cast<const bf16x8*>(&Vs[cur][16 * t + lm][colr0]);
            bf16x8 vb1 = *reinterpret_cast<const bf16x8*>(&Vs[cur][16 * t + lm][colr1]);
            oacc[t] = __builtin_amdgcn_mfma_f32_16x16x32_bf16(pa0, vb0, oacc[t], 0, 0, 0);
            oacc[t] = __builtin_amdgcn_mfma_f32_16x16x32_bf16(pa1, vb1, oacc[t], 0, 0, 0);
        }
        __builtin_amdgcn_s_setprio(0);

        if (has_next) {
            const int nxt = cur ^ 1;
            #pragma unroll
            for (int p = 0; p < 2; ++p) {
                *reinterpret_cast<bf16x8*>(&Ks[nxt][r0 + 32 * p][c8s]) = kr[p];
                *reinterpret_cast<bf16x8*>(&Vs[nxt][r0 + 32 * p][c8s]) = vr[p];
            }
        }
        __syncthreads();
    }

    #pragma unroll
    for (int r = 0; r < 4; ++r) {
        float rinv = 1.f / __shfl(lrun, 4 * lg + r);
        int n = n_base + 4 * lg + r;
        unsigned short* dst = &catT[((size_t)b * SEQN + n) * 512 + 256 + h * 64];
        #pragma unroll
        for (int t = 0; t < 4; ++t)
            dst[16 * t + lm] = f2bf(oacc[t][r] * rinv);
    }
}

// ---------------------------------------------------------------------------
// Node 2 (R5-verbatim + attn XCD swizzle): attn(512) | fuse(512) |
// x1 transpose(512) | W2 cast(128)
// ---------------------------------------------------------------------------
__global__ __launch_bounds__(256) void fused2_k(
    const unsigned short* __restrict__ qbf, const unsigned short* __restrict__ kbf,
    const unsigned short* __restrict__ vbf, const int* __restrict__ mcnt,
    unsigned short* __restrict__ catT,
    const float* __restrict__ W1, const float* __restrict__ b1,
    const float* __restrict__ gamma, const float* __restrict__ beta,
    const float* __restrict__ mean, const float* __restrict__ var,
    const float* __restrict__ Wmh, const float* __restrict__ bmh,
    unsigned short* __restrict__ Acat, float* __restrict__ cvec,
    const float* __restrict__ x1,
    const float* __restrict__ W2, unsigned short* __restrict__ W2b)
{
    __shared__ __align__(16) char smraw[41984];
    const int bid = blockIdx.x, tid = threadIdx.x;

    if (bid < 512) {
        const int xcd = bid & 7, slot = bid >> 3;
        const int p2 = xcd * 2 + (slot >> 5);
        do_attn(smraw, qbf, kbf, vbf, mcnt, catT, slot & 31, p2 & 3, p2 >> 2);
    } else if (bid < 1024) {
        const int j = bid - 512;
        const int c = tid;
        const float s = gamma[j] * rsqrtf(var[j] + 1e-5f);
        const float* w1b = W1 + (size_t)j * 512 + 256;
        Acat[(size_t)j * 512 + c] = f2bf(s * W1[(size_t)j * 512 + c]);
        float acc = 0.f;
        for (int t = 0; t < 256; ++t)
            acc += w1b[t] * Wmh[(size_t)t * 256 + c];
        Acat[(size_t)j * 512 + 256 + c] = f2bf(s * acc);
        if (c == 0) {
            float ab = 0.f;
            for (int t = 0; t < 256; ++t) ab += w1b[t] * bmh[t];
            cvec[j] = s * (b1[j] + ab - mean[j]) + beta[j];
        }
    } else if (bid < 1536) {
        const int t = bid - 1024;
        float (*Ts)[68] = reinterpret_cast<float(*)[68]>(smraw);
        const int cx = t & 3, ny = (t >> 2) & 31, b = t >> 7;
        const int c0 = cx * 64, n0 = ny * 64;
        const int cr = tid >> 2, nc = (tid & 3) * 16;
        #pragma unroll
        for (int q = 0; q < 4; ++q) {
            float4 v = *reinterpret_cast<const float4*>(
                &x1[((size_t)b * CDIM + c0 + cr) * SEQN + n0 + nc + 4 * q]);
            *reinterpret_cast<float4*>(&Ts[cr][nc + 4 * q]) = v;
        }
        __syncthreads();
        const int nr = tid >> 2, cc = (tid & 3) * 16;
        unsigned short tmp[16];
        #pragma unroll
        for (int e = 0; e < 16; ++e) tmp[e] = f2bf(Ts[cc + e][nr]);
        unsigned short* dp = &catT[((size_t)(b * SEQN + n0 + nr)) * 512 + c0 + cc];
        #pragma unroll
        for (int q = 0; q < 4; ++q)
            *reinterpret_cast<ushort4*>(&dp[4 * q]) = *reinterpret_cast<ushort4*>(&tmp[4 * q]);
    } else {
        const int cid = bid - 1536;
        const int idx = (cid * 256 + tid) * 4;
        float4 v = *reinterpret_cast<const float4*>(&W2[idx]);
        ushort4 p; p.x = f2bf(v.x); p.y = f2bf(v.y); p.z = f2bf(v.z); p.w = f2bf(v.w);
        *reinterpret_cast<ushort4*>(&W2b[idx]) = p;
    }
}

// ---------------------------------------------------------------------------
// Node 3: gemm2 (R1-proven 128x64 body), 1-D grid mod-8-invariant by decode
// ---------------------------------------------------------------------------
__global__ __launch_bounds__(256) void gemm2_k(
    const unsigned short* __restrict__ W, const unsigned short* __restrict__ X,
    const float* __restrict__ bias, unsigned short* __restrict__ obf)
{
    __shared__ short At[128][72];
    __shared__ short Bt[64][72];
    const int tid = threadIdx.x;
    const int w = tid >> 6, l = tid & 63, lm = l & 15, lg = l >> 4;
    const int g = blockIdx.x;
    const int bx = g >> 7, by = g & 127;
    const int o0 = bx * 128, ng0 = by * 64;
    const int wo = (w >> 1) * 64, wn = (w & 1) * 32;

    f32x4 acc[4][2] = {};
    const int arow = tid >> 2, acol = (tid & 3) * 16;

    for (int k0 = 0; k0 < 512; k0 += 64) {
        __syncthreads();
        #pragma unroll
        for (int p = 0; p < 2; ++p) {
            const unsigned short* s = &W[(size_t)(o0 + arow + 64 * p) * 512 + k0 + acol];
            *reinterpret_cast<bf16x8*>(&At[arow + 64 * p][acol]) =
                *reinterpret_cast<const bf16x8*>(s);
            *reinterpret_cast<bf16x8*>(&At[arow + 64 * p][acol + 8]) =
                *reinterpret_cast<const bf16x8*>(s + 8);
        }
        {
            const unsigned short* s = &X[(size_t)(ng0 + arow) * 512 + k0 + acol];
            *reinterpret_cast<bf16x8*>(&Bt[arow][acol]) =
                *reinterpret_cast<const bf16x8*>(s);
            *reinterpret_cast<bf16x8*>(&Bt[arow][acol + 8]) =
                *reinterpret_cast<const bf16x8*>(s + 8);
        }
        __syncthreads();
        #pragma unroll
        for (int kc = 0; kc < 2; ++kc) {
            bf16x8 a[4], bf[2];
            #pragma unroll
            for (int i = 0; i < 4; ++i)
                a[i] = *reinterpret_cast<const bf16x8*>(&At[wo + 16 * i + lm][kc * 32 + lg * 8]);
            #pragma unroll
            for (int j = 0; j < 2; ++j)
                bf[j] = *reinterpret_cast<const bf16x8*>(&Bt[wn + 16 * j + lm][kc * 32 + lg * 8]);
            #pragma unroll
            for (int i = 0; i < 4; ++i)
                #pragma unroll
                for (int j = 0; j < 2; ++j)
                    acc[i][j] = __builtin_amdgcn_mfma_f32_16x16x32_bf16(a[i], bf[j], acc[i][j], 0, 0, 0);
        }
    }

    #pragma unroll
    for (int j = 0; j < 2; ++j) {
        const int ng = ng0 + wn + 16 * j + lm;
        #pragma unroll
        for (int i = 0; i < 4; ++i) {
            const int ob = o0 + wo + 16 * i + 4 * lg;
            float4 bv = *reinterpret_cast<const float4*>(&bias[ob]);
            ushort4 pk;
            pk.x = f2bf(fmaxf(acc[i][j][0] + bv.x, 0.f));
            pk.y = f2bf(fmaxf(acc[i][j][1] + bv.y, 0.f));
            pk.z = f2bf(fmaxf(acc[i][j][2] + bv.z, 0.f));
            pk.w = f2bf(fmaxf(acc[i][j][3] + bv.w, 0.f));
            *reinterpret_cast<ushort4*>(&obf[(size_t)ng * 512 + ob]) = pk;
        }
    }
}

// ---------------------------------------------------------------------------
// Node 4: gemm3 retiled 64x64 (R3-proven body) -> 512 blocks, 2 blk/CU
// ---------------------------------------------------------------------------
__global__ __launch_bounds__(256) void gemm3_k(
    const unsigned short* __restrict__ W, const unsigned short* __restrict__ X,
    const float* __restrict__ bias, const float* __restrict__ res,
    float* __restrict__ ofp)
{
    __shared__ short At[64][72];
    __shared__ short Bt[64][72];
    const int tid = threadIdx.x;
    const int w = tid >> 6, l = tid & 63, lm = l & 15, lg = l >> 4;
    const int g = blockIdx.x;
    const int bx = g >> 7, by = g & 127;
    const int o0 = bx * 64, ng0 = by * 64;
    const int wo = (w >> 1) * 32, wn = (w & 1) * 32;

    f32x4 acc[2][2] = {};
    const int arow = tid >> 2, acol = (tid & 3) * 16;

    for (int k0 = 0; k0 < 512; k0 += 64) {
        __syncthreads();
        {
            const unsigned short* s = &W[(size_t)(o0 + arow) * 512 + k0 + acol];
            *reinterpret_cast<bf16x8*>(&At[arow][acol]) =
                *reinterpret_cast<const bf16x8*>(s);
            *reinterpret_cast<bf16x8*>(&At[arow][acol + 8]) =
                *reinterpret_cast<const bf16x8*>(s + 8);
        }
        {
            const unsigned short* s = &X[(size_t)(ng0 + arow) * 512 + k0 + acol];
            *reinterpret_cast<bf16x8*>(&Bt[arow][acol]) =
                *reinterpret_cast<const bf16x8*>(s);
            *reinterpret_cast<bf16x8*>(&Bt[arow][acol + 8]) =
                *reinterpret_cast<const bf16x8*>(s + 8);
        }
        __syncthreads();
        #pragma unroll
        for (int kc = 0; kc < 2; ++kc) {
            bf16x8 a[2], bf[2];
            #pragma unroll
            for (int i = 0; i < 2; ++i)
                a[i] = *reinterpret_cast<const bf16x8*>(&At[wo + 16 * i + lm][kc * 32 + lg * 8]);
            #pragma unroll
            for (int j = 0; j < 2; ++j)
                bf[j] = *reinterpret_cast<const bf16x8*>(&Bt[wn + 16 * j + lm][kc * 32 + lg * 8]);
            #pragma unroll
            for (int i = 0; i < 2; ++i)
                #pragma unroll
                for (int j = 0; j < 2; ++j)
                    acc[i][j] = __builtin_amdgcn_mfma_f32_16x16x32_bf16(a[i], bf[j], acc[i][j], 0, 0, 0);
        }
    }

    #pragma unroll
    for (int j = 0; j < 2; ++j) {
        const int ng = ng0 + wn + 16 * j + lm;
        const int b = ng >> 11, n = ng & 2047;
        #pragma unroll
        for (int i = 0; i < 2; ++i) {
            const int ob = o0 + wo + 16 * i + 4 * lg;
            float4 bv = *reinterpret_cast<const float4*>(&bias[ob]);
            float v[4] = {acc[i][j][0] + bv.x, acc[i][j][1] + bv.y,
                          acc[i][j][2] + bv.z, acc[i][j][3] + bv.w};
            #pragma unroll
            for (int r = 0; r < 4; ++r) {
                size_t ad = ((size_t)b * CDIM + ob + r) * SEQN + n;
                ofp[ad] = v[r] + res[ad];
            }
        }
    }
}

// ---------------------------------------------------------------------------
extern "C" void kernel_launch(void* const* d_in, const int* in_sizes, int n_in,
                              void* d_out, int out_size, void* d_ws, size_t ws_size,
                              hipStream_t stream)
{
    (void)in_sizes; (void)n_in; (void)out_size; (void)ws_size;
    const float* x1    = (const float*)d_in[0];
    const float* x2    = (const float*)d_in[1];
    const int*   kvm   = (const int*)  d_in[2];
    const float* Wq    = (const float*)d_in[3];
    const float* bq    = (const float*)d_in[4];
    const float* Wk    = (const float*)d_in[5];
    const float* bk    = (const float*)d_in[6];
    const float* Wv    = (const float*)d_in[7];
    const float* bv    = (const float*)d_in[8];
    const float* Wmh   = (const float*)d_in[9];
    const float* bmh   = (const float*)d_in[10];
    const float* W1    = (const float*)d_in[11];
    const float* b1    = (const float*)d_in[12];
    const float* gamma = (const float*)d_in[13];
    const float* beta  = (const float*)d_in[14];
    const float* mean  = (const float*)d_in[15];
    const float* var   = (const float*)d_in[16];
    const float* W2    = (const float*)d_in[17];
    const float* b2    = (const float*)d_in[18];
    float* out = (float*)d_out;

    const size_t act = (size_t)NB * CDIM * SEQN;        // 2,097,152
    unsigned short* ws    = (unsigned short*)d_ws;
    unsigned short* qbf   = ws;                 // act
    unsigned short* kbf   = qbf   + act;        // act
    unsigned short* vbf   = kbf   + act;        // act
    unsigned short* catT  = vbf   + act;        // 2*act (8192 x 512)
    unsigned short* hbuf  = catT  + 2 * act;    // 2*act (8192 x 512)
    unsigned short* W2b   = hbuf  + 2 * act;    // 131072
    unsigned short* Acat  = W2b   + 131072;     // 262144
    float*          cvec  = (float*)(Acat + 262144);
    int*            pidx  = (int*)(cvec + 512);          // NB*2048
    int*            mcnt  = pidx + (size_t)NB * SEQM;    // NB
    unsigned int*   rdy   = (unsigned int*)(mcnt + 16);  // NB ready flags

    const float qscale = 0.125f * 1.44269504088896f;   // fold 1/sqrt(D)*log2(e)

    // 1) Q|K|V projections (fp32-direct W and X) + compact folded in
    qkv_k<<<dim3(NB + 768), dim3(256), 0, stream>>>(
        Wq, Wk, Wv, x1, x2, bq, bk, bv, qbf, kbf, vbf,
        kvm, pidx, mcnt, rdy, qscale);

    // 2) attn -> catT[256:512] | fuse -> Acat/cvec | x1^T -> catT[0:256] | W2 cast
    fused2_k<<<dim3(1664), dim3(256), 0, stream>>>(
        qbf, kbf, vbf, mcnt, catT,
        W1, b1, gamma, beta, mean, var, Wmh, bmh, Acat, cvec,
        x1, W2, W2b);

    // 3) hidden = relu(Acat @ cat + cvec)
    gemm2_k<<<dim3(512), dim3(256), 0, stream>>>(Acat, catT, cvec, hbuf);

    // 4) out = x1 + W2 @ hidden + b2   (64x64 tiles, 512 blocks)
    gemm3_k<<<dim3(512), dim3(256), 0, stream>>>(W2b, hbuf, b2, x1, out);
}